// Round 1
// baseline (194.659 us; speedup 1.0000x reference)
//
#include <hip/hip_runtime.h>
#include <cstdint>

typedef short short8 __attribute__((ext_vector_type(8)));
typedef float floatx4 __attribute__((ext_vector_type(4)));

#define MFMA_BF16 __builtin_amdgcn_mfma_f32_16x16x32_bf16

// round-to-nearest-even fp32 -> bf16 (bits in a short)
__device__ __forceinline__ short f2bf(float f) {
  union { float f; unsigned u; } a; a.f = f;
  unsigned r = a.u + 0x7FFFu + ((a.u >> 16) & 1u);
  return (short)(r >> 16);
}

__device__ __forceinline__ float silu_f(float v) {
  return v / (1.0f + __expf(-v));
}

#define QDIM 256
#define DEMB 64
#define TILE_T 32
#define ITERS 4          // tokens per block = 128
#define NBLK1 512
#define YSTR 264         // 256 + 8 bf16 pad -> row stride 528B (2-way-free b128 reads)
#define UVSTR 132        // 128 + 4 f32 pad
#define HSTR 72          // 64 + 8 bf16 pad -> 144B rows (16B aligned)

// output layout (floats)
#define OFF_QKV 4194304
#define OFF_SW  4243456
#define OFF_WO  4276224

// ws layout (floats): [0, 8*4096) ao partial copies; [32768, 32774) sums
#define AO_COPIES 8

__global__ __launch_bounds__(256, 2) void k1_main(
    const float* __restrict__ x, const float* __restrict__ y,
    const float* __restrict__ w_sw, const float* __restrict__ w_out,
    float* __restrict__ y_out, float* __restrict__ ao_copies)
{
  __shared__ __align__(16) short Ylds[TILE_T * YSTR];
  __shared__ __align__(16) float UVlds[TILE_T * UVSTR];
  __shared__ __align__(16) short Hlds[TILE_T * HSTR];

  const int tid  = threadIdx.x;
  const int lane = tid & 63;
  const int wave = tid >> 6;
  const int l15  = lane & 15;
  const int quad = lane >> 4;
  const floatx4 fzero = {0.f, 0.f, 0.f, 0.f};

  // B1 fragments: w_swiglu rows for this wave's 32 N-cols, resident in regs.
  // B layout: lane holds B[k=quad*8+j][n=l15]; B[k][n] = w_sw[n][k] (row-major reads).
  short8 b1[2][8];
#pragma unroll
  for (int nt = 0; nt < 2; ++nt) {
    const float* wr = w_sw + (size_t)(wave * 32 + nt * 16 + l15) * QDIM;
#pragma unroll
    for (int kt = 0; kt < 8; ++kt) {
      const float* p = wr + kt * 32 + quad * 8;
      short8 f;
#pragma unroll
      for (int j = 0; j < 8; ++j) f[j] = f2bf(p[j]);
      b1[nt][kt] = f;
    }
  }
  // B2 fragments: w_out rows for this wave's 16 e-cols.
  short8 b2[2];
  {
    const float* wr = w_out + (size_t)(wave * 16 + l15) * DEMB;
#pragma unroll
    for (int kt = 0; kt < 2; ++kt) {
      const float* p = wr + kt * 32 + quad * 8;
      short8 f;
#pragma unroll
      for (int j = 0; j < 8; ++j) f[j] = f2bf(p[j]);
      b2[kt] = f;
    }
  }

  // ao accumulators: wave handles d in [wave*16, wave*16+16), e-tiles 0..3
  floatx4 ao_acc[4];
#pragma unroll
  for (int i = 0; i < 4; ++i) ao_acc[i] = fzero;

  const int tok0 = blockIdx.x * (TILE_T * ITERS);

  for (int it = 0; it < ITERS; ++it) {
    const int tbase = tok0 + it * TILE_T;

    // ---- stage Y tile (fp32 global -> bf16 LDS) ----
    {
      const float4* src = (const float4*)(y + (size_t)tbase * QDIM);
#pragma unroll
      for (int rep = 0; rep < 8; ++rep) {
        int i = tid + rep * 256;           // i in [0, 2048): float4 index
        float4 f = src[i];
        int tok = i >> 6;                  // (i*4)/256
        int col = (i & 63) * 4;
        short* dst = &Ylds[tok * YSTR + col];
        dst[0] = f2bf(f.x); dst[1] = f2bf(f.y);
        dst[2] = f2bf(f.z); dst[3] = f2bf(f.w);
      }
    }
    __syncthreads();

    // ---- UV = Ytile @ Wsw^T : wave computes 32 tokens x 32 cols ----
    floatx4 acc[2][2];
#pragma unroll
    for (int a = 0; a < 2; ++a)
#pragma unroll
      for (int b = 0; b < 2; ++b) acc[a][b] = fzero;
#pragma unroll
    for (int kt = 0; kt < 8; ++kt) {
      short8 a0 = *(const short8*)&Ylds[(l15)      * YSTR + kt * 32 + quad * 8];
      short8 a1 = *(const short8*)&Ylds[(16 + l15) * YSTR + kt * 32 + quad * 8];
      acc[0][0] = MFMA_BF16(a0, b1[0][kt], acc[0][0], 0, 0, 0);
      acc[0][1] = MFMA_BF16(a0, b1[1][kt], acc[0][1], 0, 0, 0);
      acc[1][0] = MFMA_BF16(a1, b1[0][kt], acc[1][0], 0, 0, 0);
      acc[1][1] = MFMA_BF16(a1, b1[1][kt], acc[1][1], 0, 0, 0);
    }
    // D layout: row = quad*4+r (token), col = l15 (n)
#pragma unroll
    for (int mt = 0; mt < 2; ++mt)
#pragma unroll
      for (int nt = 0; nt < 2; ++nt)
#pragma unroll
        for (int r = 0; r < 4; ++r)
          UVlds[(mt * 16 + quad * 4 + r) * UVSTR + wave * 32 + nt * 16 + l15] =
              acc[mt][nt][r];
    __syncthreads();

    // ---- h = u * silu(v) -> Hlds (bf16) ----
    {
      int t = tid >> 3;
      int d0 = (tid & 7) * 8;
      const float* uvrow = &UVlds[t * UVSTR];
      short8 pack;
#pragma unroll
      for (int j = 0; j < 8; ++j) {
        float u = uvrow[d0 + j];
        float v = uvrow[64 + d0 + j];
        pack[j] = f2bf(u * silu_f(v));
      }
      *(short8*)&Hlds[t * HSTR + d0] = pack;
    }

    // ---- ao += u^T v over this tile (K=32 tokens), persistent accumulators ----
    {
      short8 a3;  // A[m=d_local=l15][k=t=quad*8+j] = u[t][wave*16+l15]
#pragma unroll
      for (int j = 0; j < 8; ++j)
        a3[j] = f2bf(UVlds[(quad * 8 + j) * UVSTR + wave * 16 + l15]);
#pragma unroll
      for (int et = 0; et < 4; ++et) {
        short8 b3;  // B[k=t][n=e_local=l15] = v[t][et*16+l15]
#pragma unroll
        for (int j = 0; j < 8; ++j)
          b3[j] = f2bf(UVlds[(quad * 8 + j) * UVSTR + 64 + et * 16 + l15]);
        ao_acc[et] = MFMA_BF16(a3, b3, ao_acc[et], 0, 0, 0);
      }
    }
    __syncthreads();

    // ---- y_out = x + H @ Wout^T (wave's 16 e-cols) ----
#pragma unroll
    for (int mt = 0; mt < 2; ++mt) {
      floatx4 acc2 = fzero;
#pragma unroll
      for (int kt = 0; kt < 2; ++kt) {
        short8 a2 = *(const short8*)&Hlds[(mt * 16 + l15) * HSTR + kt * 32 + quad * 8];
        acc2 = MFMA_BF16(a2, b2[kt], acc2, 0, 0, 0);
      }
      int e = wave * 16 + l15;
#pragma unroll
      for (int r = 0; r < 4; ++r) {
        size_t idx = (size_t)(tbase + mt * 16 + quad * 4 + r) * DEMB + e;
        y_out[idx] = x[idx] + acc2[r];
      }
    }
    __syncthreads();
  }

  // flush ao partials (one of 8 copies to cut atomic contention)
  float* dst = ao_copies + (blockIdx.x & (AO_COPIES - 1)) * 4096;
#pragma unroll
  for (int et = 0; et < 4; ++et)
#pragma unroll
    for (int r = 0; r < 4; ++r) {
      int d = wave * 16 + quad * 4 + r;
      int e = et * 16 + l15;
      atomicAdd(&dst[d * 64 + e], ao_acc[et][r]);
    }
}

// candidates + per-matrix sum/sumsq; 4 rows per block (wave per row)
__global__ __launch_bounds__(256) void k3_updates(
    const float* __restrict__ w_qkv, const float* __restrict__ w_sw,
    const float* __restrict__ w_out, const float* __restrict__ out_w,
    const float* __restrict__ ao_copies, float* __restrict__ out,
    float* __restrict__ sums)
{
  __shared__ float aoN[64 * 64];
  const int tid = threadIdx.x;

  // finalize ao: sum 8 copies, /64 (= /B * 64^-0.5), rms-norm each row
  if (tid < 64) {
    float ss = 0.f;
    for (int a = 0; a < 64; ++a) {
      float v = 0.f;
#pragma unroll
      for (int c = 0; c < AO_COPIES; ++c) v += ao_copies[c * 4096 + tid * 64 + a];
      v *= (1.0f / 64.0f);
      aoN[tid * 64 + a] = v;
      ss += v * v;
    }
    float sc = rsqrtf(ss * (1.0f / 64.0f) + 1.1920929e-07f);
    for (int a = 0; a < 64; ++a) aoN[tid * 64 + a] *= sc;
  }
  __syncthreads();

  const int lane = tid & 63;
  const int wave = tid >> 6;
  const int rid  = blockIdx.x * 4 + wave;   // [0, 1344)

  float wlane;
  int matrix, out_idx;
  if (rid < 768) {                 // w_qkv row
    wlane = w_qkv[rid * 64 + lane];
    matrix = 0; out_idx = OFF_QKV + rid * 64 + lane;
  } else if (rid < 1280) {         // swiglu b-column of the [64,512] view
    int b = rid - 768;
    wlane = w_sw[lane * 512 + b];  // M[a=lane][b], flat = w_sw.flat
    matrix = 1; out_idx = OFF_SW + lane * 512 + b;
  } else {                         // w_out row
    int r = rid - 1280;
    wlane = w_out[r * 64 + lane];
    matrix = 2; out_idx = OFF_WO + r * 64 + lane;
  }

  // s[d=lane] = sum_a wrow[a] * ao[a][d]
  float s = 0.f;
  for (int a = 0; a < 64; ++a)
    s += __shfl(wlane, a) * aoN[a * 64 + lane];
  float n = silu_f(s);
  // val[c=lane] = wrow[c] + sum_d n[d] * out_w[c][d]
  float val = wlane;
  for (int d = 0; d < 64; ++d)
    val += __shfl(n, d) * out_w[lane * 64 + d];

  out[out_idx] = val;

  float s1 = val, s2 = val * val;
#pragma unroll
  for (int off = 32; off > 0; off >>= 1) {
    s1 += __shfl_down(s1, off);
    s2 += __shfl_down(s2, off);
  }
  if (lane == 0) {
    atomicAdd(&sums[matrix * 2],     s1);
    atomicAdd(&sums[matrix * 2 + 1], s2);
  }
}

__global__ __launch_bounds__(256) void k4_scale(
    float* __restrict__ out, const float* __restrict__ sums,
    const float* __restrict__ tao)
{
  int i = blockIdx.x * 256 + threadIdx.x;   // [0, 86016)
  int matrix, idx; float N, tstd;
  if (i < 49152)      { matrix = 0; idx = OFF_QKV + i;           N = 49152.f; tstd = 0.125f;  }
  else if (i < 81920) { matrix = 1; idx = OFF_SW + (i - 49152);  N = 32768.f; tstd = 0.0625f; }
  else                { matrix = 2; idx = OFF_WO + (i - 81920);  N = 4096.f;  tstd = 0.0625f; }
  float sum = sums[matrix * 2], sumsq = sums[matrix * 2 + 1];
  float mean = sum / N;
  float var  = (sumsq - N * mean * mean) / (N - 1.f);   // ddof=1
  float sd   = sqrtf(fmaxf(var, 0.f));
  float g    = fminf(fmaxf(fabsf(tao[matrix]), 1e-8f), 1.0f);
  out[idx] *= g * tstd / (sd + 1e-8f);
}

extern "C" void kernel_launch(void* const* d_in, const int* in_sizes, int n_in,
                              void* d_out, int out_size, void* d_ws, size_t ws_size,
                              hipStream_t stream) {
  const float* x     = (const float*)d_in[0];
  const float* y     = (const float*)d_in[1];
  const float* w_qkv = (const float*)d_in[2];
  const float* w_sw  = (const float*)d_in[3];
  const float* w_out = (const float*)d_in[4];
  const float* out_w = (const float*)d_in[5];
  const float* tao   = (const float*)d_in[6];
  float* out = (float*)d_out;
  float* ws  = (float*)d_ws;

  float* ao_copies = ws;                    // 8*4096 floats
  float* sums      = ws + AO_COPIES * 4096; // 6 floats

  hipMemsetAsync(d_ws, 0, (AO_COPIES * 4096 + 8) * sizeof(float), stream);
  k1_main<<<dim3(NBLK1), dim3(256), 0, stream>>>(x, y, w_sw, w_out, out, ao_copies);
  k3_updates<<<dim3(336), dim3(256), 0, stream>>>(w_qkv, w_sw, w_out, out_w,
                                                  ao_copies, out, sums);
  k4_scale<<<dim3(336), dim3(256), 0, stream>>>(out, sums, tao);
}

// Round 2
// 145.631 us; speedup vs baseline: 1.3367x; 1.3367x over previous
//
#include <hip/hip_runtime.h>
#include <cstdint>

typedef short short8 __attribute__((ext_vector_type(8)));
typedef float floatx4 __attribute__((ext_vector_type(4)));

#define MFMA_BF16 __builtin_amdgcn_mfma_f32_16x16x32_bf16

// round-to-nearest-even fp32 -> bf16 (bits in a short)
__device__ __forceinline__ short f2bf(float f) {
  union { float f; unsigned u; } a; a.f = f;
  unsigned r = a.u + 0x7FFFu + ((a.u >> 16) & 1u);
  return (short)(r >> 16);
}

__device__ __forceinline__ float silu_f(float v) {
  return v / (1.0f + __expf(-v));
}

#define QDIM 256
#define DEMB 64
#define TILE_T 32
#define ITERS 4          // tokens per block = 128
#define NBLK1 512
#define YSTR 264         // 256 + 8 bf16 pad
#define UVSTR 132        // 128 + 4 f32 pad
#define HSTR 72          // 64 + 8 bf16 pad

// output layout (floats)
#define OFF_QKV 4194304
#define OFF_SW  4243456
#define OFF_WO  4276224

// ws layout (floats): [0, 32768) ao partial copies; [32768, 32776) sums;
// byte 131104: aoT bf16 [64 e][64 d] (4096 ushorts)
#define AO_COPIES 8
#define WS_SUMS   32768
#define WS_AOT    32776   // float index; byte 131104 (16-aligned)

// ============================ K1: streaming ============================
__global__ __launch_bounds__(256, 2) void k1_main(
    const float* __restrict__ x, const float* __restrict__ y,
    const float* __restrict__ w_sw, const float* __restrict__ w_out,
    float* __restrict__ y_out, float* __restrict__ ao_copies)
{
  __shared__ __align__(16) short Ylds[TILE_T * YSTR];
  __shared__ __align__(16) float UVlds[TILE_T * UVSTR];
  __shared__ __align__(16) short Hlds[TILE_T * HSTR];

  const int tid  = threadIdx.x;
  const int lane = tid & 63;
  const int wave = tid >> 6;
  const int l15  = lane & 15;
  const int quad = lane >> 4;
  const floatx4 fzero = {0.f, 0.f, 0.f, 0.f};

  short8 b1[2][8];
#pragma unroll
  for (int nt = 0; nt < 2; ++nt) {
    const float* wr = w_sw + (size_t)(wave * 32 + nt * 16 + l15) * QDIM;
#pragma unroll
    for (int kt = 0; kt < 8; ++kt) {
      const float* p = wr + kt * 32 + quad * 8;
      short8 f;
#pragma unroll
      for (int j = 0; j < 8; ++j) f[j] = f2bf(p[j]);
      b1[nt][kt] = f;
    }
  }
  short8 b2[2];
  {
    const float* wr = w_out + (size_t)(wave * 16 + l15) * DEMB;
#pragma unroll
    for (int kt = 0; kt < 2; ++kt) {
      const float* p = wr + kt * 32 + quad * 8;
      short8 f;
#pragma unroll
      for (int j = 0; j < 8; ++j) f[j] = f2bf(p[j]);
      b2[kt] = f;
    }
  }

  floatx4 ao_acc[4];
#pragma unroll
  for (int i = 0; i < 4; ++i) ao_acc[i] = fzero;

  const int tok0 = blockIdx.x * (TILE_T * ITERS);

  for (int it = 0; it < ITERS; ++it) {
    const int tbase = tok0 + it * TILE_T;

    {
      const float4* src = (const float4*)(y + (size_t)tbase * QDIM);
#pragma unroll
      for (int rep = 0; rep < 8; ++rep) {
        int i = tid + rep * 256;
        float4 f = src[i];
        int tok = i >> 6;
        int col = (i & 63) * 4;
        short* dst = &Ylds[tok * YSTR + col];
        dst[0] = f2bf(f.x); dst[1] = f2bf(f.y);
        dst[2] = f2bf(f.z); dst[3] = f2bf(f.w);
      }
    }
    __syncthreads();

    floatx4 acc[2][2];
#pragma unroll
    for (int a = 0; a < 2; ++a)
#pragma unroll
      for (int b = 0; b < 2; ++b) acc[a][b] = fzero;
#pragma unroll
    for (int kt = 0; kt < 8; ++kt) {
      short8 a0 = *(const short8*)&Ylds[(l15)      * YSTR + kt * 32 + quad * 8];
      short8 a1 = *(const short8*)&Ylds[(16 + l15) * YSTR + kt * 32 + quad * 8];
      acc[0][0] = MFMA_BF16(a0, b1[0][kt], acc[0][0], 0, 0, 0);
      acc[0][1] = MFMA_BF16(a0, b1[1][kt], acc[0][1], 0, 0, 0);
      acc[1][0] = MFMA_BF16(a1, b1[0][kt], acc[1][0], 0, 0, 0);
      acc[1][1] = MFMA_BF16(a1, b1[1][kt], acc[1][1], 0, 0, 0);
    }
#pragma unroll
    for (int mt = 0; mt < 2; ++mt)
#pragma unroll
      for (int nt = 0; nt < 2; ++nt)
#pragma unroll
        for (int r = 0; r < 4; ++r)
          UVlds[(mt * 16 + quad * 4 + r) * UVSTR + wave * 32 + nt * 16 + l15] =
              acc[mt][nt][r];
    __syncthreads();

    {
      int t = tid >> 3;
      int d0 = (tid & 7) * 8;
      const float* uvrow = &UVlds[t * UVSTR];
      short8 pack;
#pragma unroll
      for (int j = 0; j < 8; ++j) {
        float u = uvrow[d0 + j];
        float v = uvrow[64 + d0 + j];
        pack[j] = f2bf(u * silu_f(v));
      }
      *(short8*)&Hlds[t * HSTR + d0] = pack;
    }

    {
      short8 a3;
#pragma unroll
      for (int j = 0; j < 8; ++j)
        a3[j] = f2bf(UVlds[(quad * 8 + j) * UVSTR + wave * 16 + l15]);
#pragma unroll
      for (int et = 0; et < 4; ++et) {
        short8 b3;
#pragma unroll
        for (int j = 0; j < 8; ++j)
          b3[j] = f2bf(UVlds[(quad * 8 + j) * UVSTR + 64 + et * 16 + l15]);
        ao_acc[et] = MFMA_BF16(a3, b3, ao_acc[et], 0, 0, 0);
      }
    }
    __syncthreads();

#pragma unroll
    for (int mt = 0; mt < 2; ++mt) {
      floatx4 acc2 = fzero;
#pragma unroll
      for (int kt = 0; kt < 2; ++kt) {
        short8 a2 = *(const short8*)&Hlds[(mt * 16 + l15) * HSTR + kt * 32 + quad * 8];
        acc2 = MFMA_BF16(a2, b2[kt], acc2, 0, 0, 0);
      }
      int e = wave * 16 + l15;
#pragma unroll
      for (int r = 0; r < 4; ++r) {
        size_t idx = (size_t)(tbase + mt * 16 + quad * 4 + r) * DEMB + e;
        y_out[idx] = x[idx] + acc2[r];
      }
    }
    __syncthreads();
  }

  float* dst = ao_copies + (blockIdx.x & (AO_COPIES - 1)) * 4096;
#pragma unroll
  for (int et = 0; et < 4; ++et)
#pragma unroll
    for (int r = 0; r < 4; ++r) {
      int d = wave * 16 + quad * 4 + r;
      int e = et * 16 + l15;
      atomicAdd(&dst[d * 64 + e], ao_acc[et][r]);
    }
}

// ================== K2: finalize ao -> bf16 aoT in ws ==================
// aoT[e*64 + d] = rms_norm_rows(sum_copies(ao)/64)[d][e], bf16.
// All global loads lane-stride-1; LDS transposed with +1 pad (no 64-way bank hits).
__global__ __launch_bounds__(256) void k2_finalize(
    const float* __restrict__ ao_copies, unsigned short* __restrict__ aoT)
{
  __shared__ float aoFT[64 * 65];   // [e][d], pad 65
  __shared__ float ssPart[256];
  __shared__ float scRow[64];
  const int tid = threadIdx.x;

  // Phase A: coalesced sum of 8 copies, store transposed
#pragma unroll
  for (int k = 0; k < 16; ++k) {
    int idx = k * 256 + tid;          // = d*64 + e
    float v = 0.f;
#pragma unroll
    for (int c = 0; c < AO_COPIES; ++c) v += ao_copies[c * 4096 + idx];
    v *= (1.0f / 64.0f);              // /B * n_embd^-0.5
    int d = idx >> 6, e = idx & 63;
    aoFT[e * 65 + d] = v;
  }
  __syncthreads();

  // Phase B: ss per row d (4 threads/row, each 16 e's)
  {
    int d = tid >> 2, q = tid & 3;
    float ssp = 0.f;
#pragma unroll
    for (int e2 = 0; e2 < 16; ++e2) {
      float v = aoFT[(q * 16 + e2) * 65 + d];
      ssp += v * v;
    }
    ssPart[tid] = ssp;
  }
  __syncthreads();
  if (tid < 64) {
    float ss = ssPart[tid * 4] + ssPart[tid * 4 + 1] +
               ssPart[tid * 4 + 2] + ssPart[tid * 4 + 3];
    scRow[tid] = rsqrtf(ss * (1.0f / 64.0f) + 1.1920929e-07f);
  }
  __syncthreads();

  // Phase C: scaled bf16 write, coalesced in d (aoT row e contiguous in d)
#pragma unroll
  for (int k = 0; k < 16; ++k) {
    int j = k * 256 + tid;            // = e*64 + d
    int e = j >> 6, d = j & 63;
    float v = aoFT[e * 65 + d] * scRow[d];
    aoT[j] = (unsigned short)f2bf(v);
  }
}

// ============ K3: weight-update candidates via MFMA (84 waves) =========
// rid<48: w_qkv 16-row tile; 48<=rid<80: swiglu-view 16-p tile (transposed
// formulation C2^T = W2^T + out_w . N2^T); rid>=80: w_out 16-row tile.
__global__ __launch_bounds__(64) void k3_updates(
    const float* __restrict__ w_qkv, const float* __restrict__ w_sw,
    const float* __restrict__ w_out, const float* __restrict__ out_w,
    const unsigned short* __restrict__ aoT, float* __restrict__ out,
    float* __restrict__ sums)
{
  __shared__ __align__(16) short Nlds[16 * 72];   // N tile [m][d], pad 72
  const int lane = threadIdx.x;
  const int l15  = lane & 15;
  const int quad = lane >> 4;
  const int rid  = blockIdx.x;      // [0, 84)
  const floatx4 fzero = {0.f, 0.f, 0.f, 0.f};
  const short8* aoTv = (const short8*)aoT;

  // B1 frags: B[k=d][n=e] = aoN[d][e] = aoT[e*64+d] -> b128 loads
  short8 bf[2][4];
#pragma unroll
  for (int kt = 0; kt < 2; ++kt)
#pragma unroll
    for (int nt = 0; nt < 4; ++nt)
      bf[kt][nt] = aoTv[(nt * 16 + l15) * 8 + kt * 4 + quad];

  // A1 frags: A[m=l15][k=d] = W[row][d]
  short8 af[2];
  if (rid < 48) {
    const float* wr = w_qkv + (size_t)(rid * 16 + l15) * 64;
#pragma unroll
    for (int kt = 0; kt < 2; ++kt) {
      const float* p = wr + kt * 32 + quad * 8;
      short8 f;
#pragma unroll
      for (int j = 0; j < 8; ++j) f[j] = f2bf(p[j]);
      af[kt] = f;
    }
  } else if (rid < 80) {
    int p0 = (rid - 48) * 16;
#pragma unroll
    for (int kt = 0; kt < 2; ++kt) {
      short8 f;
#pragma unroll
      for (int j = 0; j < 8; ++j) {
        int a = kt * 32 + quad * 8 + j;
        f[j] = f2bf(w_sw[a * 512 + p0 + l15]);
      }
      af[kt] = f;
    }
  } else {
    const float* wr = w_out + (size_t)((rid - 80) * 16 + l15) * 64;
#pragma unroll
    for (int kt = 0; kt < 2; ++kt) {
      const float* p = wr + kt * 32 + quad * 8;
      short8 f;
#pragma unroll
      for (int j = 0; j < 8; ++j) f[j] = f2bf(p[j]);
      af[kt] = f;
    }
  }

  // Stage 1: S = W . aoN ; N = silu(S) -> Nlds
  floatx4 acc[4];
#pragma unroll
  for (int nt = 0; nt < 4; ++nt) acc[nt] = fzero;
#pragma unroll
  for (int kt = 0; kt < 2; ++kt)
#pragma unroll
    for (int nt = 0; nt < 4; ++nt)
      acc[nt] = MFMA_BF16(af[kt], bf[kt][nt], acc[nt], 0, 0, 0);
#pragma unroll
  for (int nt = 0; nt < 4; ++nt)
#pragma unroll
    for (int r = 0; r < 4; ++r)
      Nlds[(quad * 4 + r) * 72 + nt * 16 + l15] = f2bf(silu_f(acc[nt][r]));
  __syncthreads();   // single wave: just a waitcnt fence

  float s1 = 0.f, s2 = 0.f;
  int matrix;

  if (rid < 48 || rid >= 80) {
    matrix = (rid < 48) ? 0 : 2;
    // Stage 2: C = W + N . out_w^T
    short8 a2[2];
#pragma unroll
    for (int kt = 0; kt < 2; ++kt)
      a2[kt] = *(const short8*)&Nlds[l15 * 72 + kt * 32 + quad * 8];
    short8 b2[2][4];
#pragma unroll
    for (int nt = 0; nt < 4; ++nt) {
      const float* wr = out_w + (size_t)(nt * 16 + l15) * 64;
#pragma unroll
      for (int kt = 0; kt < 2; ++kt) {
        const float* p = wr + kt * 32 + quad * 8;
        short8 f;
#pragma unroll
        for (int j = 0; j < 8; ++j) f[j] = f2bf(p[j]);
        b2[kt][nt] = f;
      }
    }
    floatx4 acc2[4];
#pragma unroll
    for (int nt = 0; nt < 4; ++nt) acc2[nt] = fzero;
#pragma unroll
    for (int kt = 0; kt < 2; ++kt)
#pragma unroll
      for (int nt = 0; nt < 4; ++nt)
        acc2[nt] = MFMA_BF16(a2[kt], b2[kt][nt], acc2[nt], 0, 0, 0);

    const float* Wsrc = (rid < 48) ? w_qkv : w_out;
    int base_row = (rid < 48) ? rid * 16 : (rid - 80) * 16;
    int off      = (rid < 48) ? OFF_QKV : OFF_WO;
#pragma unroll
    for (int nt = 0; nt < 4; ++nt)
#pragma unroll
      for (int r = 0; r < 4; ++r) {
        int row = base_row + quad * 4 + r;
        int col = nt * 16 + l15;
        float val = Wsrc[row * 64 + col] + acc2[nt][r];
        out[off + row * 64 + col] = val;
        s1 += val; s2 += val * val;
      }
  } else {
    matrix = 1;
    int p0 = (rid - 48) * 16;
    // Stage 2: C2^T = W2^T + out_w . N2^T  (B-frag of N^T == A-frag of N)
    short8 b2[2];
#pragma unroll
    for (int kt = 0; kt < 2; ++kt)
      b2[kt] = *(const short8*)&Nlds[l15 * 72 + kt * 32 + quad * 8];
    short8 a2[4][2];
#pragma unroll
    for (int mt = 0; mt < 4; ++mt) {
      const float* wr = out_w + (size_t)(mt * 16 + l15) * 64;
#pragma unroll
      for (int kt = 0; kt < 2; ++kt) {
        const float* p = wr + kt * 32 + quad * 8;
        short8 f;
#pragma unroll
        for (int j = 0; j < 8; ++j) f[j] = f2bf(p[j]);
        a2[mt][kt] = f;
      }
    }
    floatx4 acc2[4];
#pragma unroll
    for (int mt = 0; mt < 4; ++mt) acc2[mt] = fzero;
#pragma unroll
    for (int mt = 0; mt < 4; ++mt)
#pragma unroll
      for (int kt = 0; kt < 2; ++kt)
        acc2[mt] = MFMA_BF16(a2[mt][kt], b2[kt], acc2[mt], 0, 0, 0);
#pragma unroll
    for (int mt = 0; mt < 4; ++mt)
#pragma unroll
      for (int r = 0; r < 4; ++r) {
        int a = mt * 16 + quad * 4 + r;
        int p = p0 + l15;
        int idx = a * 512 + p;
        float val = w_sw[idx] + acc2[mt][r];
        out[OFF_SW + idx] = val;
        s1 += val; s2 += val * val;
      }
  }

  // wave reduce + one atomic pair
#pragma unroll
  for (int off = 32; off > 0; off >>= 1) {
    s1 += __shfl_down(s1, off);
    s2 += __shfl_down(s2, off);
  }
  if (lane == 0) {
    atomicAdd(&sums[matrix * 2],     s1);
    atomicAdd(&sums[matrix * 2 + 1], s2);
  }
}

// ============================ K4: final scale ==========================
__global__ __launch_bounds__(256) void k4_scale(
    float* __restrict__ out, const float* __restrict__ sums,
    const float* __restrict__ tao)
{
  int i = blockIdx.x * 256 + threadIdx.x;
  int matrix, idx; float N, tstd;
  if (i < 49152)      { matrix = 0; idx = OFF_QKV + i;           N = 49152.f; tstd = 0.125f;  }
  else if (i < 81920) { matrix = 1; idx = OFF_SW + (i - 49152);  N = 32768.f; tstd = 0.0625f; }
  else                { matrix = 2; idx = OFF_WO + (i - 81920);  N = 4096.f;  tstd = 0.0625f; }
  float sum = sums[matrix * 2], sumsq = sums[matrix * 2 + 1];
  float mean = sum / N;
  float var  = (sumsq - N * mean * mean) / (N - 1.f);
  float sd   = sqrtf(fmaxf(var, 0.f));
  float g    = fminf(fmaxf(fabsf(tao[matrix]), 1e-8f), 1.0f);
  out[idx] *= g * tstd / (sd + 1e-8f);
}

extern "C" void kernel_launch(void* const* d_in, const int* in_sizes, int n_in,
                              void* d_out, int out_size, void* d_ws, size_t ws_size,
                              hipStream_t stream) {
  const float* x     = (const float*)d_in[0];
  const float* y     = (const float*)d_in[1];
  const float* w_qkv = (const float*)d_in[2];
  const float* w_sw  = (const float*)d_in[3];
  const float* w_out = (const float*)d_in[4];
  const float* out_w = (const float*)d_in[5];
  const float* tao   = (const float*)d_in[6];
  float* out = (float*)d_out;
  float* ws  = (float*)d_ws;

  float* ao_copies    = ws;
  float* sums         = ws + WS_SUMS;
  unsigned short* aoT = (unsigned short*)(ws + WS_AOT);

  hipMemsetAsync(d_ws, 0, (WS_SUMS + 8) * sizeof(float), stream);
  k1_main<<<dim3(NBLK1), dim3(256), 0, stream>>>(x, y, w_sw, w_out, out, ao_copies);
  k2_finalize<<<dim3(1), dim3(256), 0, stream>>>(ao_copies, aoT);
  k3_updates<<<dim3(84), dim3(64), 0, stream>>>(w_qkv, w_sw, w_out, out_w,
                                                aoT, out, sums);
  k4_scale<<<dim3(336), dim3(256), 0, stream>>>(out, sums, tao);
}